// Round 14
// baseline (183.683 us; speedup 1.0000x reference)
//
#include <hip/hip_runtime.h>
#include <hip/hip_bf16.h>

// DARTS MixedOp. B=64, C=128, H=W=32. Per-sample top-k(2) masked-softmax gate
// over 8 ops. Inputs fp32, outputs fp32.
//
// R24: revert R23's dual-accumulator (canary: +3.8us, VGPR occupancy flip),
//  keep the zero-register half of the idea: pw_final n==1 fast path
//  (block-uniform; majority of samples select <=1 conv op) = bit-copy
//  staging + gs folded into the STORE with the single acc[8]. n>=2 path is
//  R22 verbatim (scaled staging, accumulate across ops). Fast-path numerics
//  already validated by R23 (passed, absmax unchanged).
//  k_front (2-plane) / k_sep unchanged from R22.
//
// ws: gates @0 | cnum @2048 | cops @2304 | Wbf[6][128][128] bf16 @4096 |
// 6 bf16 bufs of 16.8MB @200704 (A4 A5 P4 P5 P6 P7) = ~101MB.

#define BN_SCALE 0.9999950000374997f  // 1/sqrt(1+1e-5)
#define BB 64
#define CC 128
#define HH 32
#define WW 32
#define PLANE (HH*WW)          // 1024
#define SAMP (CC*PLANE)        // 131072
#define NOUT0 (BB*SAMP)        // 8388608
#define FRONT_MAIN (BB*CC/2)   // 4096 main blocks, 2 planes each

typedef __attribute__((ext_vector_type(8))) short bf16x8;
typedef __attribute__((ext_vector_type(4))) float f32x4;

__device__ __forceinline__ float us2f(unsigned int u) {
    unsigned int x = (u & 0xffffu) << 16;
    float f; __builtin_memcpy(&f, &x, 4); return f;
}
__device__ __forceinline__ unsigned short f2us(float f) {
    __hip_bfloat16 h = __float2bfloat16(f);
    unsigned short u; __builtin_memcpy(&u, &h, 2); return u;
}

// ---------------------------------------------------------------- gates
__device__ __forceinline__ void compute_gates(const float* __restrict__ wlog,
                                              const void* __restrict__ topp,
                                              int b, float* g) {
    int top = -1;                           // robust `top` parse
    {
        unsigned int u0 = *(const unsigned int*)topp;
        int i32 = (int)u0;
        if (i32 >= 1 && i32 <= 8) top = i32;
        else {
            float f32v; __builtin_memcpy(&f32v, &u0, 4);
            if (f32v >= 1.f && f32v <= 8.f) top = (int)(f32v + 0.5f);
            else { float fb = us2f(u0); if (fb >= 1.f && fb <= 8.f) top = (int)(fb + 0.5f); }
        }
        if (top < 1 || top > 8) top = 2;
    }
    float lw[8];
    #pragma unroll
    for (int i = 0; i < 8; ++i) lw[i] = wlog[b * 8 + i];
    bool sel[8] = {false,false,false,false,false,false,false,false};
    for (int t = 0; t < top; ++t) {         // lax.top_k tie-break: lowest index
        int best = -1; float bv = -3.4e38f;
        #pragma unroll
        for (int i = 0; i < 8; ++i)
            if (!sel[i] && lw[i] > bv) { bv = lw[i]; best = i; }
        if (best >= 0) sel[best] = true;
    }
    float m = -3.4e38f;
    #pragma unroll
    for (int i = 0; i < 8; ++i) if (sel[i] && lw[i] > m) m = lw[i];
    float s = 0.f, e[8];
    #pragma unroll
    for (int i = 0; i < 8; ++i) { e[i] = sel[i] ? expf(lw[i] - m) : 0.f; s += e[i]; }
    float inv = (s > 0.f) ? 1.f / s : 0.f;
    #pragma unroll
    for (int i = 0; i < 8; ++i)
        g[i] = (s > 0.f) ? e[i] * inv : (sel[i] ? 1.f / (float)top : 0.f);
}

// ---------------- depthwise conv, contiguous-4px windowed form ----------
template <int K, int DIL>
__device__ __forceinline__ void dw_comp4(const float* __restrict__ sx,
                                         const float* __restrict__ wd, int c,
                                         unsigned short* __restrict__ opp) {
    constexpr int PAD = (K / 2) * DIL;     // 1,2,2,4 -- always <= 4
    float wk[K * K];
    #pragma unroll
    for (int i = 0; i < K * K; ++i) wk[i] = wd[c * K * K + i];
    int h = threadIdx.x >> 3;
    int q = threadIdx.x & 7;
    int w0 = q * 4;
    float acc[4] = {0.f, 0.f, 0.f, 0.f};
    #pragma unroll
    for (int ky = 0; ky < K; ++ky) {
        int ih = h + ky * DIL - PAD;
        if ((unsigned)ih >= HH) continue;
        const float4* row4 = (const float4*)(sx + ih * WW);
        float4 Lm = row4[q > 0 ? q - 1 : 0];
        float4 L0 = row4[q];
        float4 Lp = row4[q < 7 ? q + 1 : 7];
        if (q == 0) Lm = make_float4(0.f, 0.f, 0.f, 0.f);
        if (q == 7) Lp = make_float4(0.f, 0.f, 0.f, 0.f);
        float win[12] = {Lm.x, Lm.y, Lm.z, Lm.w,
                         L0.x, L0.y, L0.z, L0.w,
                         Lp.x, Lp.y, Lp.z, Lp.w};
        #pragma unroll
        for (int kx = 0; kx < K; ++kx) {
            float f = wk[ky * K + kx];
            #pragma unroll
            for (int j = 0; j < 4; ++j)
                acc[j] = fmaf(f, win[4 + j + kx * DIL - PAD], acc[j]);
        }
    }
    ushort4 o;
    o.x = f2us(acc[0]); o.y = f2us(acc[1]);
    o.z = f2us(acc[2]); o.w = f2us(acc[3]);
    *(ushort4*)(opp + h * WW + w0) = o;
}

// ------- K1: pools + skip + out init + first dw of all 4 conv ops for
//             TWO consecutive c-planes of one sample per block, plus
//             (aux blocks) weight prep and gate-buffer writes.
__global__ __launch_bounds__(256) void
k_front_all(const float* __restrict__ x,
            const float* __restrict__ w4, const float* __restrict__ w5,
            const float* __restrict__ w6, const float* __restrict__ w7,
            const float* __restrict__ wlog, const void* __restrict__ topp,
            const float* __restrict__ pw0, const float* __restrict__ pw1,
            const float* __restrict__ pw2, const float* __restrict__ pw3,
            const float* __restrict__ pw4, const float* __restrict__ pw5,
            float* __restrict__ gates,
            int* __restrict__ cnum, int* __restrict__ cops,
            float* __restrict__ out_w,
            unsigned short* __restrict__ Wbf,
            float* __restrict__ out,
            unsigned short* __restrict__ A4, unsigned short* __restrict__ A5,
            unsigned short* __restrict__ P6, unsigned short* __restrict__ P7) {
    if (blockIdx.x >= FRONT_MAIN) {
        int aux = blockIdx.x - FRONT_MAIN;
        if (aux < 384) {                         // pw weight fp32->bf16 prep
            int idx = aux * 256 + threadIdx.x;   // 6*16384 = 384*256
            int mat = idx >> 14, e = idx & 16383;
            const float* src; float s = 1.f;
            switch (mat) {                       // block-uniform
                case 0:  src = pw0; s = BN_SCALE; break;  // sc3_p1 (mid, BN folded)
                case 1:  src = pw1; s = BN_SCALE; break;  // sc5_p1
                case 2:  src = pw2; break;                // sc3_p2
                case 3:  src = pw3; break;                // sc5_p2
                case 4:  src = pw4; break;                // dc3_p
                default: src = pw5; break;                // dc5_p
            }
            Wbf[idx] = f2us(src[e] * s);
        } else if (threadIdx.x < BB) {           // gate-buffer role block
            int b = threadIdx.x;
            float g[8];
            compute_gates(wlog, topp, b, g);
            #pragma unroll
            for (int i = 0; i < 8; ++i) {
                out_w[b * 8 + i] = wlog[b * 8 + i];   // output 1: logit clone
                gates[b * 8 + i] = g[i];
            }
            int n = 0;
            #pragma unroll
            for (int i = 4; i < 8; ++i)
                if (g[i] > 0.f) { if (n < 4) cops[b * 4 + n] = i; ++n; }
            cnum[b] = (n < 4) ? n : 4;
        }
        return;
    }
    int plane0 = blockIdx.x * 2;       // 2 consecutive c of one b (128%2==0)
    int b = plane0 >> 7, c0 = plane0 & 127;
    __shared__ float sg[8];
    __shared__ float sxr[2][PLANE];    // raw x (pools/skip)
    __shared__ float sxf[2][PLANE];    // relu(x) (dw)
    if (threadIdx.x == 0) {            // gates by one thread, hidden under
        float g[8];                    // the other threads' staging
        compute_gates(wlog, topp, b, g);
        #pragma unroll
        for (int i = 0; i < 8; ++i) sg[i] = g[i];
    }
    {
        // 2 independent loads issued back-to-back: one exposed HBM latency.
        float4 v0 = ((const float4*)(x + (size_t)(plane0 + 0) * PLANE))[threadIdx.x];
        float4 v1 = ((const float4*)(x + (size_t)(plane0 + 1) * PLANE))[threadIdx.x];
        ((float4*)sxr[0])[threadIdx.x] = v0;
        ((float4*)sxr[1])[threadIdx.x] = v1;
        ((float4*)sxf[0])[threadIdx.x] =
            make_float4(fmaxf(v0.x, 0.f), fmaxf(v0.y, 0.f),
                        fmaxf(v0.z, 0.f), fmaxf(v0.w, 0.f));
        ((float4*)sxf[1])[threadIdx.x] =
            make_float4(fmaxf(v1.x, 0.f), fmaxf(v1.y, 0.f),
                        fmaxf(v1.z, 0.f), fmaxf(v1.w, 0.f));
    }
    __syncthreads();
    float g1 = sg[1] * BN_SCALE;
    float g2 = sg[2] * BN_SCALE;
    float g3 = sg[3];
    float g4 = sg[4], g5 = sg[5], g6 = sg[6], g7 = sg[7];
    bool haspool = (g1 != 0.f) | (g2 != 0.f);
    bool hasconv = (g4 != 0.f) | (g5 != 0.f) | (g6 != 0.f) | (g7 != 0.f);

    // ---- out init per plane (R19 logic verbatim).
    if (haspool) {
        int h = threadIdx.x >> 3;
        int q = threadIdx.x & 7;
        int w0 = q * 4;
        int rv = 3 - (h == 0) - (h == HH - 1);
        float cj0 = (float)(rv * (3 - (w0 == 0)));
        float cjm = (float)(rv * 3);
        float cj3 = (float)(rv * (3 - (w0 + 3 == WW - 1)));
        #pragma unroll
        for (int p = 0; p < 2; ++p) {
            float* op = out + (size_t)(plane0 + p) * PLANE;
            float mx[4] = {-3.4e38f, -3.4e38f, -3.4e38f, -3.4e38f};
            float sm[4] = {0.f, 0.f, 0.f, 0.f};
            #pragma unroll
            for (int dh = -1; dh <= 1; ++dh) {
                int ih = h + dh;
                if ((unsigned)ih >= HH) continue;
                const float4* row4 = (const float4*)(sxr[p] + ih * WW);
                float4 Lm = row4[q > 0 ? q - 1 : 0];
                float4 L0 = row4[q];
                float4 Lp = row4[q < 7 ? q + 1 : 7];
                if (q == 0) Lm = make_float4(0.f, 0.f, 0.f, 0.f);
                if (q == 7) Lp = make_float4(0.f, 0.f, 0.f, 0.f);
                float win[12] = {Lm.x, Lm.y, Lm.z, Lm.w,
                                 L0.x, L0.y, L0.z, L0.w,
                                 Lp.x, Lp.y, Lp.z, Lp.w};
                #pragma unroll
                for (int j = 0; j < 4; ++j) {
                    sm[j] = sm[j] + win[3 + j];
                    sm[j] = sm[j] + win[4 + j];
                    sm[j] = sm[j] + win[5 + j];
                    float a  = (w0 + j - 1 >= 0) ? win[3 + j] : -3.4e38f;
                    float bq = (w0 + j + 1 < WW) ? win[5 + j] : -3.4e38f;
                    mx[j] = fmaxf(mx[j], a);
                    mx[j] = fmaxf(mx[j], win[4 + j]);
                    mx[j] = fmaxf(mx[j], bq);
                }
            }
            const float4* rmid = (const float4*)(sxr[p] + h * WW);
            float4 xm = rmid[q];
            float4 o;
            o.x = g1 * mx[0] + g2 * (sm[0] / cj0) + g3 * xm.x;
            o.y = g1 * mx[1] + g2 * (sm[1] / cjm) + g3 * xm.y;
            o.z = g1 * mx[2] + g2 * (sm[2] / cjm) + g3 * xm.z;
            o.w = g1 * mx[3] + g2 * (sm[3] / cj3) + g3 * xm.w;
            *(float4*)(op + h * WW + w0) = o;
        }
    } else if (g3 != 0.f) {            // skip-only: vector scale
        #pragma unroll
        for (int p = 0; p < 2; ++p) {
            float4 v = ((const float4*)sxr[p])[threadIdx.x];
            ((float4*)(out + (size_t)(plane0 + p) * PLANE))[threadIdx.x] =
                make_float4(g3 * v.x, g3 * v.y, g3 * v.z, g3 * v.w);
        }
    } else if (!hasconv) {             // nothing at all: zeros
        #pragma unroll
        for (int p = 0; p < 2; ++p)
            ((float4*)(out + (size_t)(plane0 + p) * PLANE))[threadIdx.x] =
                make_float4(0.f, 0.f, 0.f, 0.f);
    }
    // else: conv-only sample -- pw_final plain-stores, no init needed.

    // ---- first dw for gated conv ops, per plane
    if (g4 != 0.f) {
        #pragma unroll
        for (int p = 0; p < 2; ++p)
            dw_comp4<3, 1>(sxf[p], w4, c0 + p, A4 + (size_t)(plane0 + p) * PLANE);
    }
    if (g5 != 0.f) {
        #pragma unroll
        for (int p = 0; p < 2; ++p)
            dw_comp4<5, 1>(sxf[p], w5, c0 + p, A5 + (size_t)(plane0 + p) * PLANE);
    }
    if (g6 != 0.f) {
        #pragma unroll
        for (int p = 0; p < 2; ++p)
            dw_comp4<3, 2>(sxf[p], w6, c0 + p, P6 + (size_t)(plane0 + p) * PLANE);
    }
    if (g7 != 0.f) {
        #pragma unroll
        for (int p = 0; p < 2; ++p)
            dw_comp4<5, 2>(sxf[p], w7, c0 + p, P7 + (size_t)(plane0 + p) * PLANE);
    }
}

// ---------------- MFMA pw building blocks -------------------------------
// Orientation: m=hw, n=co. A = In^T tile (LDS, 64hw x 128ci, row stride 130
// ushorts = 65 dwords -> bank stride 1), B = W bf16 (direct global, L2-hot).

__device__ __forceinline__ void stage_bt(unsigned int* __restrict__ BtU,
                                         const unsigned short* __restrict__ A,
                                         int hw0, float s) {
    unsigned short* Bs = (unsigned short*)BtU;
    #pragma unroll
    for (int i = 0; i < 16; ++i) {
        int idx = threadIdx.x + i * 256;       // 4096 = 128ci x 32 hw-pairs
        int ci = idx >> 5, p = idx & 31;
        unsigned int raw = *(const unsigned int*)(A + (size_t)ci * PLANE + hw0 + 2 * p);
        Bs[(2 * p) * 130 + ci]     = f2us(us2f(raw) * s);
        Bs[(2 * p + 1) * 130 + ci] = f2us(us2f(raw >> 16) * s);
    }
}

// pure bit-copy staging (no float ops) -- n==1 fast path in pw_final.
__device__ __forceinline__ void stage_bt_copy(unsigned int* __restrict__ BtU,
                                              const unsigned short* __restrict__ A,
                                              int hw0) {
    unsigned short* Bs = (unsigned short*)BtU;
    #pragma unroll
    for (int i = 0; i < 16; ++i) {
        int idx = threadIdx.x + i * 256;
        int ci = idx >> 5, p = idx & 31;
        unsigned int raw = *(const unsigned int*)(A + (size_t)ci * PLANE + hw0 + 2 * p);
        Bs[(2 * p) * 130 + ci]     = (unsigned short)(raw & 0xffffu);
        Bs[(2 * p + 1) * 130 + ci] = (unsigned short)(raw >> 16);
    }
}

// zero-padded variant for halo rows (hw0 may run off the plane); unroll-4
// (R13's spill-free profile for the k_sep code shape).
__device__ __forceinline__ void stage_bt_z(unsigned int* __restrict__ BtU,
                                           const unsigned short* __restrict__ A,
                                           int hw0) {
    unsigned short* Bs = (unsigned short*)BtU;
    #pragma unroll 4
    for (int i = 0; i < 16; ++i) {
        int idx = threadIdx.x + i * 256;
        int ci = idx >> 5, p = idx & 31;
        int pg = hw0 + 2 * p;
        unsigned int raw = 0u;
        if ((unsigned)pg < (unsigned)PLANE)
            raw = *(const unsigned int*)(A + (size_t)ci * PLANE + pg);
        Bs[(2 * p) * 130 + ci]     = (unsigned short)(raw & 0xffffu);
        Bs[(2 * p + 1) * 130 + ci] = (unsigned short)(raw >> 16);
    }
}

__device__ __forceinline__ bf16x8 afrag(const unsigned int* __restrict__ BtU,
                                        int r, int ko2) {
    union { unsigned int u[4]; bf16x8 v; } f;
    #pragma unroll
    for (int j = 0; j < 4; ++j) f.u[j] = BtU[r * 65 + ko2 + j];
    return f.v;
}

// ---- fused sep tile: mid-pw over K+1 halo rows (MFMA, relu'd bf16 into
//      Braw LDS), then dw2 via chunked register sliding window; dw output
//      written DIRECTLY to global P (bf16, unscaled -- pw_final applies gs).
template <int K>
__device__ __forceinline__ void
sep_tile(unsigned int* __restrict__ BtU, unsigned short* __restrict__ Braw,
         const unsigned short* __restrict__ Asrc,
         const unsigned short* __restrict__ Wmid,
         const float* __restrict__ wd, int hwt,
         unsigned short* __restrict__ Pout) {
    constexpr int PAD = K / 2, NR = K + 1, NSEG = NR / 2, S = 196;
    int wave = threadIdx.x >> 6, lane = threadIdx.x & 63;
    int q = lane >> 4, mm = lane & 15;
    int r = wave * 16 + mm;
    int rbase = 2 * hwt - PAD;                 // first staged image row
    for (int seg = 0; seg < NSEG; ++seg) {
        if (seg) __syncthreads();              // prev seg's afrag reads done
        stage_bt_z(BtU, Asrc, rbase * 32 + seg * 64);
        __syncthreads();
        f32x4 accB[8];
        #pragma unroll
        for (int i = 0; i < 8; ++i) accB[i] = (f32x4){0.f, 0.f, 0.f, 0.f};
        #pragma unroll
        for (int kb = 0; kb < 4; ++kb) {
            bf16x8 a = afrag(BtU, r, kb * 16 + q * 4);
            #pragma unroll
            for (int nt = 0; nt < 8; ++nt) {
                bf16x8 bv = *(const bf16x8*)(Wmid + (nt * 16 + mm) * CC + kb * 32 + q * 8);
                accB[nt] = __builtin_amdgcn_mfma_f32_16x16x32_bf16(a, bv, accB[nt], 0, 0, 0);
            }
        }
        int pxb = seg * 64 + wave * 16 + q * 4;   // local px within NR rows
        #pragma unroll
        for (int nt = 0; nt < 8; ++nt) {
            int co = nt * 16 + mm;
            ushort4 v;
            v.x = f2us(fmaxf(accB[nt][0], 0.f));   // relu folded (bit-equal to
            v.y = f2us(fmaxf(accB[nt][1], 0.f));   // round-then-relu for bf16)
            v.z = f2us(fmaxf(accB[nt][2], 0.f));
            v.w = f2us(fmaxf(accB[nt][3], 0.f));
            *(ushort4*)(Braw + (size_t)co * S + pxb) = v;
        }
    }
    __syncthreads();                           // Braw complete

    // dw2 KxK: thread (ci, h) computes output row 2*hwt+h, cols 0..31.
    // Chunked 8-col sliding window (R12's spill-safe shape).
    int ci = threadIdx.x & 127, h = threadIdx.x >> 7;
    float wk[K * K];
    #pragma unroll
    for (int i = 0; i < K * K; ++i) wk[i] = wd[ci * K * K + i];
    const unsigned short* rowp = Braw + (size_t)ci * S + h * 32;
    unsigned short* po = Pout + (size_t)ci * PLANE + (2 * hwt + h) * 32;
    #pragma unroll
    for (int w0 = 0; w0 < 32; w0 += 8) {
        float acc[8];
        #pragma unroll
        for (int w = 0; w < 8; ++w) acc[w] = 0.f;
        #pragma unroll
        for (int ky = 0; ky < K; ++ky) {       // input row = h + ky
            float win[16];                     // cols w0-4 .. w0+11
            #pragma unroll
            for (int k = 0; k < 4; ++k) {
                int col = w0 - 4 + 4 * k;      // 4-col groups: all-in or all-out
                if ((unsigned)col < 32u) {
                    ushort4 v = *(const ushort4*)(rowp + ky * 32 + col);
                    win[4*k]   = us2f(v.x);
                    win[4*k+1] = us2f(v.y);
                    win[4*k+2] = us2f(v.z);
                    win[4*k+3] = us2f(v.w);
                } else {
                    win[4*k] = win[4*k+1] = win[4*k+2] = win[4*k+3] = 0.f;
                }
            }
            #pragma unroll
            for (int kx = 0; kx < K; ++kx) {
                float f = wk[ky * K + kx];
                #pragma unroll
                for (int w = 0; w < 8; ++w)
                    acc[w] = fmaf(f, win[w + kx - PAD + 4], acc[w]);
            }
        }
        ushort4 o0, o1;
        o0.x = f2us(acc[0]); o0.y = f2us(acc[1]);
        o0.z = f2us(acc[2]); o0.w = f2us(acc[3]);
        o1.x = f2us(acc[4]); o1.y = f2us(acc[5]);
        o1.z = f2us(acc[6]); o1.w = f2us(acc[7]);
        *(ushort4*)(po + w0)     = o0;
        *(ushort4*)(po + w0 + 4) = o1;
    }
}

// ------------- K2: fused mid-pw + dw2 for sep ops, one op per block.
// grid = BB*32: blk -> (b, opi, hwt); ~512 active blocks = one full-device
// round at 2 blocks/CU (LDS 67KB). No cross-op accumulator, no atomics.
__global__ __launch_bounds__(256) void
k_sep(const unsigned short* __restrict__ A4,
      const unsigned short* __restrict__ A5,
      const unsigned short* __restrict__ Wbf,
      const float* __restrict__ gates,
      const float* __restrict__ wd3, const float* __restrict__ wd5,
      unsigned short* __restrict__ P4, unsigned short* __restrict__ P5) {
    int blk = blockIdx.x;              // b*32 + opi*16 + hwt
    int hwt = blk & 15;
    int opi = (blk >> 4) & 1;
    int b = blk >> 5;
    if (gates[b * 8 + 4 + opi] == 0.f) return;
    __shared__ unsigned int BtU[64 * 65];           // 16.6 KB
    __shared__ unsigned short Braw[128 * 196];      // 50.2 KB
    if (opi == 0)
        sep_tile<3>(BtU, Braw, A4 + (size_t)b * SAMP, Wbf, wd3, hwt,
                    P4 + (size_t)b * SAMP);
    else
        sep_tile<5>(BtU, Braw, A5 + (size_t)b * SAMP, Wbf + 16384, wd5, hwt,
                    P5 + (size_t)b * SAMP);
}

// ------------- K3: final pw, gated instances; n==1 fast path (bit-copy
// staging, gs folded into the store -- zero extra registers), n>=2 = R22
// path (gs in staging, accumulate). RMW into out when pools/skip
// initialized it, plain store for conv-only samples.
__global__ __launch_bounds__(256) void
k_pw_final(const unsigned short* __restrict__ P4,
           const unsigned short* __restrict__ P5,
           const unsigned short* __restrict__ P6,
           const unsigned short* __restrict__ P7,
           const unsigned short* __restrict__ Wbf,
           const float* __restrict__ gates,
           const int* __restrict__ cnum, const int* __restrict__ cops,
           float* __restrict__ out) {
    int blk = blockIdx.x;              // b*16 + hwt
    int hwt = blk & 15;
    int b = blk >> 4;
    int n = cnum[b];
    if (n == 0) return;                // out already holds pools/skip/zeros
    bool poolskip = (gates[b * 8 + 1] != 0.f) | (gates[b * 8 + 2] != 0.f) |
                    (gates[b * 8 + 3] != 0.f);
    int hw0 = hwt * 64;
    int wave = threadIdx.x >> 6, lane = threadIdx.x & 63;
    int q = lane >> 4, mm = lane & 15;
    int r = wave * 16 + mm;
    __shared__ unsigned int BtU[64 * 65];
    f32x4 acc[8];
    #pragma unroll
    for (int i = 0; i < 8; ++i) acc[i] = (f32x4){0.f, 0.f, 0.f, 0.f};
    float gpost = 1.f;                 // n==1: gs applied at store
    if (n == 1) {
        int op = cops[b * 4];
        gpost = gates[b * 8 + op] * BN_SCALE;
        const unsigned short* src;
        switch (op) {
            case 4:  src = P4; break;
            case 5:  src = P5; break;
            case 6:  src = P6; break;
            default: src = P7; break;
        }
        stage_bt_copy(BtU, src + (size_t)b * SAMP, hw0);
        __syncthreads();
        const unsigned short* Wb = Wbf + (op - 2) * 16384;
        #pragma unroll
        for (int kb = 0; kb < 4; ++kb) {
            bf16x8 a = afrag(BtU, r, kb * 16 + q * 4);
            #pragma unroll
            for (int nt = 0; nt < 8; ++nt) {
                bf16x8 bv = *(const bf16x8*)(Wb + (nt * 16 + mm) * CC + kb * 32 + q * 8);
                acc[nt] = __builtin_amdgcn_mfma_f32_16x16x32_bf16(a, bv, acc[nt], 0, 0, 0);
            }
        }
    } else {
        for (int t = 0; t < n; ++t) {
            int op = cops[b * 4 + t];
            float gs = gates[b * 8 + op] * BN_SCALE;
            const unsigned short* src;
            switch (op) {
                case 4:  src = P4; break;
                case 5:  src = P5; break;
                case 6:  src = P6; break;
                default: src = P7; break;
            }
            if (t) __syncthreads();
            stage_bt(BtU, src + (size_t)b * SAMP, hw0, gs);
            __syncthreads();
            const unsigned short* Wb = Wbf + (op - 2) * 16384;
            #pragma unroll
            for (int kb = 0; kb < 4; ++kb) {
                bf16x8 a = afrag(BtU, r, kb * 16 + q * 4);
                #pragma unroll
                for (int nt = 0; nt < 8; ++nt) {
                    bf16x8 bv = *(const bf16x8*)(Wb + (nt * 16 + mm) * CC + kb * 32 + q * 8);
                    acc[nt] = __builtin_amdgcn_mfma_f32_16x16x32_bf16(a, bv, acc[nt], 0, 0, 0);
                }
            }
        }
    }
    int hwbase = hw0 + wave * 16 + q * 4;
    if (poolskip) {
        #pragma unroll
        for (int nt = 0; nt < 8; ++nt) {
            int co = nt * 16 + mm;
            float* p = out + (size_t)(b * CC + co) * PLANE + hwbase;
            float4 o = *(float4*)p;
            o.x = fmaf(gpost, acc[nt][0], o.x);
            o.y = fmaf(gpost, acc[nt][1], o.y);
            o.z = fmaf(gpost, acc[nt][2], o.z);
            o.w = fmaf(gpost, acc[nt][3], o.w);
            *(float4*)p = o;
        }
    } else {
        #pragma unroll
        for (int nt = 0; nt < 8; ++nt) {
            int co = nt * 16 + mm;
            float* p = out + (size_t)(b * CC + co) * PLANE + hwbase;
            *(float4*)p = make_float4(gpost * acc[nt][0], gpost * acc[nt][1],
                                      gpost * acc[nt][2], gpost * acc[nt][3]);
        }
    }
}

// ---------------------------------------------------------------- launch
extern "C" void kernel_launch(void* const* d_in, const int* in_sizes, int n_in,
                              void* d_out, int out_size, void* d_ws, size_t ws_size,
                              hipStream_t stream) {
    const float* x      = (const float*)d_in[0];
    const float* wlog   = (const float*)d_in[1];
    const float* sc3_d1 = (const float*)d_in[2];
    const float* sc3_p1 = (const float*)d_in[3];
    const float* sc3_d2 = (const float*)d_in[4];
    const float* sc3_p2 = (const float*)d_in[5];
    const float* sc5_d1 = (const float*)d_in[6];
    const float* sc5_p1 = (const float*)d_in[7];
    const float* sc5_d2 = (const float*)d_in[8];
    const float* sc5_p2 = (const float*)d_in[9];
    const float* dc3_d  = (const float*)d_in[10];
    const float* dc3_p  = (const float*)d_in[11];
    const float* dc5_d  = (const float*)d_in[12];
    const float* dc5_p  = (const float*)d_in[13];
    const void* topp    = d_in[14];

    float* out  = (float*)d_out;
    float* outw = out + NOUT0;

    float* gates = (float*)d_ws;
    int*   cnum  = (int*)((char*)d_ws + 2048);
    int*   cops  = (int*)((char*)d_ws + 2304);
    unsigned short* Wbf  = (unsigned short*)((char*)d_ws + 4096);   // 6*32KB
    unsigned short* base = (unsigned short*)((char*)d_ws + 200704);
    unsigned short* A4 = base;
    unsigned short* A5 = base + (size_t)NOUT0;
    unsigned short* P4 = base + (size_t)NOUT0 * 2;
    unsigned short* P5 = base + (size_t)NOUT0 * 3;
    unsigned short* P6 = base + (size_t)NOUT0 * 4;
    unsigned short* P7 = base + (size_t)NOUT0 * 5;

    k_front_all<<<FRONT_MAIN + 385, 256, 0, stream>>>(
        x, sc3_d1, sc5_d1, dc3_d, dc5_d,
        wlog, topp,
        sc3_p1, sc5_p1, sc3_p2, sc5_p2, dc3_p, dc5_p,
        gates, cnum, cops, outw, Wbf,
        out, A4, A5, P6, P7);
    k_sep<<<BB * 32, 256, 0, stream>>>(A4, A5, Wbf, gates,
                                       sc3_d2, sc5_d2, P4, P5);
    k_pw_final<<<BB * 16, 256, 0, stream>>>(P4, P5, P6, P7, Wbf,
                                            gates, cnum, cops, out);
}

// Round 15
// 177.975 us; speedup vs baseline: 1.0321x; 1.0321x over previous
//
#include <hip/hip_runtime.h>
#include <hip/hip_bf16.h>

// DARTS MixedOp. B=64, C=128, H=W=32. Per-sample top-k(2) masked-softmax gate
// over 8 ops. Inputs fp32, outputs fp32.
//
// R25: exact revert to R22 (session best, 178.9us). R23/R24's pw_final
//  staging-VALU cuts both regressed (+3.8/+4.8us) -> pw_final is latency/
//  launch-floor bound, not staging-VALU bound; structural perturbations only
//  disturb codegen. Plateau arithmetic: 179 = 82 (2 harness 268MB poisons at
//  ~82% HBM peak, roofline-bound, untouchable) + ~10 dispatch overhead +
//  ~87 for 3 dependent kernels (pure-BW floor ~30; residual is serial
//  dispatch latency ramps -- fusion disproven R11-R16, atomics disproven
//  R14-R16).
//
// ws: gates @0 | cnum @2048 | cops @2304 | Wbf[6][128][128] bf16 @4096 |
// 6 bf16 bufs of 16.8MB @200704 (A4 A5 P4 P5 P6 P7) = ~101MB.

#define BN_SCALE 0.9999950000374997f  // 1/sqrt(1+1e-5)
#define BB 64
#define CC 128
#define HH 32
#define WW 32
#define PLANE (HH*WW)          // 1024
#define SAMP (CC*PLANE)        // 131072
#define NOUT0 (BB*SAMP)        // 8388608
#define FRONT_MAIN (BB*CC/2)   // 4096 main blocks, 2 planes each

typedef __attribute__((ext_vector_type(8))) short bf16x8;
typedef __attribute__((ext_vector_type(4))) float f32x4;

__device__ __forceinline__ float us2f(unsigned int u) {
    unsigned int x = (u & 0xffffu) << 16;
    float f; __builtin_memcpy(&f, &x, 4); return f;
}
__device__ __forceinline__ unsigned short f2us(float f) {
    __hip_bfloat16 h = __float2bfloat16(f);
    unsigned short u; __builtin_memcpy(&u, &h, 2); return u;
}

// ---------------------------------------------------------------- gates
__device__ __forceinline__ void compute_gates(const float* __restrict__ wlog,
                                              const void* __restrict__ topp,
                                              int b, float* g) {
    int top = -1;                           // robust `top` parse
    {
        unsigned int u0 = *(const unsigned int*)topp;
        int i32 = (int)u0;
        if (i32 >= 1 && i32 <= 8) top = i32;
        else {
            float f32v; __builtin_memcpy(&f32v, &u0, 4);
            if (f32v >= 1.f && f32v <= 8.f) top = (int)(f32v + 0.5f);
            else { float fb = us2f(u0); if (fb >= 1.f && fb <= 8.f) top = (int)(fb + 0.5f); }
        }
        if (top < 1 || top > 8) top = 2;
    }
    float lw[8];
    #pragma unroll
    for (int i = 0; i < 8; ++i) lw[i] = wlog[b * 8 + i];
    bool sel[8] = {false,false,false,false,false,false,false,false};
    for (int t = 0; t < top; ++t) {         // lax.top_k tie-break: lowest index
        int best = -1; float bv = -3.4e38f;
        #pragma unroll
        for (int i = 0; i < 8; ++i)
            if (!sel[i] && lw[i] > bv) { bv = lw[i]; best = i; }
        if (best >= 0) sel[best] = true;
    }
    float m = -3.4e38f;
    #pragma unroll
    for (int i = 0; i < 8; ++i) if (sel[i] && lw[i] > m) m = lw[i];
    float s = 0.f, e[8];
    #pragma unroll
    for (int i = 0; i < 8; ++i) { e[i] = sel[i] ? expf(lw[i] - m) : 0.f; s += e[i]; }
    float inv = (s > 0.f) ? 1.f / s : 0.f;
    #pragma unroll
    for (int i = 0; i < 8; ++i)
        g[i] = (s > 0.f) ? e[i] * inv : (sel[i] ? 1.f / (float)top : 0.f);
}

// ---------------- depthwise conv, contiguous-4px windowed form ----------
template <int K, int DIL>
__device__ __forceinline__ void dw_comp4(const float* __restrict__ sx,
                                         const float* __restrict__ wd, int c,
                                         unsigned short* __restrict__ opp) {
    constexpr int PAD = (K / 2) * DIL;     // 1,2,2,4 -- always <= 4
    float wk[K * K];
    #pragma unroll
    for (int i = 0; i < K * K; ++i) wk[i] = wd[c * K * K + i];
    int h = threadIdx.x >> 3;
    int q = threadIdx.x & 7;
    int w0 = q * 4;
    float acc[4] = {0.f, 0.f, 0.f, 0.f};
    #pragma unroll
    for (int ky = 0; ky < K; ++ky) {
        int ih = h + ky * DIL - PAD;
        if ((unsigned)ih >= HH) continue;
        const float4* row4 = (const float4*)(sx + ih * WW);
        float4 Lm = row4[q > 0 ? q - 1 : 0];
        float4 L0 = row4[q];
        float4 Lp = row4[q < 7 ? q + 1 : 7];
        if (q == 0) Lm = make_float4(0.f, 0.f, 0.f, 0.f);
        if (q == 7) Lp = make_float4(0.f, 0.f, 0.f, 0.f);
        float win[12] = {Lm.x, Lm.y, Lm.z, Lm.w,
                         L0.x, L0.y, L0.z, L0.w,
                         Lp.x, Lp.y, Lp.z, Lp.w};
        #pragma unroll
        for (int kx = 0; kx < K; ++kx) {
            float f = wk[ky * K + kx];
            #pragma unroll
            for (int j = 0; j < 4; ++j)
                acc[j] = fmaf(f, win[4 + j + kx * DIL - PAD], acc[j]);
        }
    }
    ushort4 o;
    o.x = f2us(acc[0]); o.y = f2us(acc[1]);
    o.z = f2us(acc[2]); o.w = f2us(acc[3]);
    *(ushort4*)(opp + h * WW + w0) = o;
}

// ------- K1: pools + skip + out init + first dw of all 4 conv ops for
//             TWO consecutive c-planes of one sample per block, plus
//             (aux blocks) weight prep and gate-buffer writes.
__global__ __launch_bounds__(256) void
k_front_all(const float* __restrict__ x,
            const float* __restrict__ w4, const float* __restrict__ w5,
            const float* __restrict__ w6, const float* __restrict__ w7,
            const float* __restrict__ wlog, const void* __restrict__ topp,
            const float* __restrict__ pw0, const float* __restrict__ pw1,
            const float* __restrict__ pw2, const float* __restrict__ pw3,
            const float* __restrict__ pw4, const float* __restrict__ pw5,
            float* __restrict__ gates,
            int* __restrict__ cnum, int* __restrict__ cops,
            float* __restrict__ out_w,
            unsigned short* __restrict__ Wbf,
            float* __restrict__ out,
            unsigned short* __restrict__ A4, unsigned short* __restrict__ A5,
            unsigned short* __restrict__ P6, unsigned short* __restrict__ P7) {
    if (blockIdx.x >= FRONT_MAIN) {
        int aux = blockIdx.x - FRONT_MAIN;
        if (aux < 384) {                         // pw weight fp32->bf16 prep
            int idx = aux * 256 + threadIdx.x;   // 6*16384 = 384*256
            int mat = idx >> 14, e = idx & 16383;
            const float* src; float s = 1.f;
            switch (mat) {                       // block-uniform
                case 0:  src = pw0; s = BN_SCALE; break;  // sc3_p1 (mid, BN folded)
                case 1:  src = pw1; s = BN_SCALE; break;  // sc5_p1
                case 2:  src = pw2; break;                // sc3_p2
                case 3:  src = pw3; break;                // sc5_p2
                case 4:  src = pw4; break;                // dc3_p
                default: src = pw5; break;                // dc5_p
            }
            Wbf[idx] = f2us(src[e] * s);
        } else if (threadIdx.x < BB) {           // gate-buffer role block
            int b = threadIdx.x;
            float g[8];
            compute_gates(wlog, topp, b, g);
            #pragma unroll
            for (int i = 0; i < 8; ++i) {
                out_w[b * 8 + i] = wlog[b * 8 + i];   // output 1: logit clone
                gates[b * 8 + i] = g[i];
            }
            int n = 0;
            #pragma unroll
            for (int i = 4; i < 8; ++i)
                if (g[i] > 0.f) { if (n < 4) cops[b * 4 + n] = i; ++n; }
            cnum[b] = (n < 4) ? n : 4;
        }
        return;
    }
    int plane0 = blockIdx.x * 2;       // 2 consecutive c of one b (128%2==0)
    int b = plane0 >> 7, c0 = plane0 & 127;
    __shared__ float sg[8];
    __shared__ float sxr[2][PLANE];    // raw x (pools/skip)
    __shared__ float sxf[2][PLANE];    // relu(x) (dw)
    if (threadIdx.x == 0) {            // gates by one thread, hidden under
        float g[8];                    // the other threads' staging
        compute_gates(wlog, topp, b, g);
        #pragma unroll
        for (int i = 0; i < 8; ++i) sg[i] = g[i];
    }
    {
        // 2 independent loads issued back-to-back: one exposed HBM latency.
        float4 v0 = ((const float4*)(x + (size_t)(plane0 + 0) * PLANE))[threadIdx.x];
        float4 v1 = ((const float4*)(x + (size_t)(plane0 + 1) * PLANE))[threadIdx.x];
        ((float4*)sxr[0])[threadIdx.x] = v0;
        ((float4*)sxr[1])[threadIdx.x] = v1;
        ((float4*)sxf[0])[threadIdx.x] =
            make_float4(fmaxf(v0.x, 0.f), fmaxf(v0.y, 0.f),
                        fmaxf(v0.z, 0.f), fmaxf(v0.w, 0.f));
        ((float4*)sxf[1])[threadIdx.x] =
            make_float4(fmaxf(v1.x, 0.f), fmaxf(v1.y, 0.f),
                        fmaxf(v1.z, 0.f), fmaxf(v1.w, 0.f));
    }
    __syncthreads();
    float g1 = sg[1] * BN_SCALE;
    float g2 = sg[2] * BN_SCALE;
    float g3 = sg[3];
    float g4 = sg[4], g5 = sg[5], g6 = sg[6], g7 = sg[7];
    bool haspool = (g1 != 0.f) | (g2 != 0.f);
    bool hasconv = (g4 != 0.f) | (g5 != 0.f) | (g6 != 0.f) | (g7 != 0.f);

    // ---- out init per plane (R19 logic verbatim).
    if (haspool) {
        int h = threadIdx.x >> 3;
        int q = threadIdx.x & 7;
        int w0 = q * 4;
        int rv = 3 - (h == 0) - (h == HH - 1);
        float cj0 = (float)(rv * (3 - (w0 == 0)));
        float cjm = (float)(rv * 3);
        float cj3 = (float)(rv * (3 - (w0 + 3 == WW - 1)));
        #pragma unroll
        for (int p = 0; p < 2; ++p) {
            float* op = out + (size_t)(plane0 + p) * PLANE;
            float mx[4] = {-3.4e38f, -3.4e38f, -3.4e38f, -3.4e38f};
            float sm[4] = {0.f, 0.f, 0.f, 0.f};
            #pragma unroll
            for (int dh = -1; dh <= 1; ++dh) {
                int ih = h + dh;
                if ((unsigned)ih >= HH) continue;
                const float4* row4 = (const float4*)(sxr[p] + ih * WW);
                float4 Lm = row4[q > 0 ? q - 1 : 0];
                float4 L0 = row4[q];
                float4 Lp = row4[q < 7 ? q + 1 : 7];
                if (q == 0) Lm = make_float4(0.f, 0.f, 0.f, 0.f);
                if (q == 7) Lp = make_float4(0.f, 0.f, 0.f, 0.f);
                float win[12] = {Lm.x, Lm.y, Lm.z, Lm.w,
                                 L0.x, L0.y, L0.z, L0.w,
                                 Lp.x, Lp.y, Lp.z, Lp.w};
                #pragma unroll
                for (int j = 0; j < 4; ++j) {
                    sm[j] = sm[j] + win[3 + j];
                    sm[j] = sm[j] + win[4 + j];
                    sm[j] = sm[j] + win[5 + j];
                    float a  = (w0 + j - 1 >= 0) ? win[3 + j] : -3.4e38f;
                    float bq = (w0 + j + 1 < WW) ? win[5 + j] : -3.4e38f;
                    mx[j] = fmaxf(mx[j], a);
                    mx[j] = fmaxf(mx[j], win[4 + j]);
                    mx[j] = fmaxf(mx[j], bq);
                }
            }
            const float4* rmid = (const float4*)(sxr[p] + h * WW);
            float4 xm = rmid[q];
            float4 o;
            o.x = g1 * mx[0] + g2 * (sm[0] / cj0) + g3 * xm.x;
            o.y = g1 * mx[1] + g2 * (sm[1] / cjm) + g3 * xm.y;
            o.z = g1 * mx[2] + g2 * (sm[2] / cjm) + g3 * xm.z;
            o.w = g1 * mx[3] + g2 * (sm[3] / cj3) + g3 * xm.w;
            *(float4*)(op + h * WW + w0) = o;
        }
    } else if (g3 != 0.f) {            // skip-only: vector scale
        #pragma unroll
        for (int p = 0; p < 2; ++p) {
            float4 v = ((const float4*)sxr[p])[threadIdx.x];
            ((float4*)(out + (size_t)(plane0 + p) * PLANE))[threadIdx.x] =
                make_float4(g3 * v.x, g3 * v.y, g3 * v.z, g3 * v.w);
        }
    } else if (!hasconv) {             // nothing at all: zeros
        #pragma unroll
        for (int p = 0; p < 2; ++p)
            ((float4*)(out + (size_t)(plane0 + p) * PLANE))[threadIdx.x] =
                make_float4(0.f, 0.f, 0.f, 0.f);
    }
    // else: conv-only sample -- pw_final plain-stores, no init needed.

    // ---- first dw for gated conv ops, per plane
    if (g4 != 0.f) {
        #pragma unroll
        for (int p = 0; p < 2; ++p)
            dw_comp4<3, 1>(sxf[p], w4, c0 + p, A4 + (size_t)(plane0 + p) * PLANE);
    }
    if (g5 != 0.f) {
        #pragma unroll
        for (int p = 0; p < 2; ++p)
            dw_comp4<5, 1>(sxf[p], w5, c0 + p, A5 + (size_t)(plane0 + p) * PLANE);
    }
    if (g6 != 0.f) {
        #pragma unroll
        for (int p = 0; p < 2; ++p)
            dw_comp4<3, 2>(sxf[p], w6, c0 + p, P6 + (size_t)(plane0 + p) * PLANE);
    }
    if (g7 != 0.f) {
        #pragma unroll
        for (int p = 0; p < 2; ++p)
            dw_comp4<5, 2>(sxf[p], w7, c0 + p, P7 + (size_t)(plane0 + p) * PLANE);
    }
}

// ---------------- MFMA pw building blocks -------------------------------
// Orientation: m=hw, n=co. A = In^T tile (LDS, 64hw x 128ci, row stride 130
// ushorts = 65 dwords -> bank stride 1), B = W bf16 (direct global, L2-hot).

__device__ __forceinline__ void stage_bt(unsigned int* __restrict__ BtU,
                                         const unsigned short* __restrict__ A,
                                         int hw0, float s) {
    unsigned short* Bs = (unsigned short*)BtU;
    #pragma unroll
    for (int i = 0; i < 16; ++i) {
        int idx = threadIdx.x + i * 256;       // 4096 = 128ci x 32 hw-pairs
        int ci = idx >> 5, p = idx & 31;
        unsigned int raw = *(const unsigned int*)(A + (size_t)ci * PLANE + hw0 + 2 * p);
        Bs[(2 * p) * 130 + ci]     = f2us(us2f(raw) * s);
        Bs[(2 * p + 1) * 130 + ci] = f2us(us2f(raw >> 16) * s);
    }
}

// zero-padded variant for halo rows (hw0 may run off the plane); unroll-4
// (R13's spill-free profile for the k_sep code shape).
__device__ __forceinline__ void stage_bt_z(unsigned int* __restrict__ BtU,
                                           const unsigned short* __restrict__ A,
                                           int hw0) {
    unsigned short* Bs = (unsigned short*)BtU;
    #pragma unroll 4
    for (int i = 0; i < 16; ++i) {
        int idx = threadIdx.x + i * 256;
        int ci = idx >> 5, p = idx & 31;
        int pg = hw0 + 2 * p;
        unsigned int raw = 0u;
        if ((unsigned)pg < (unsigned)PLANE)
            raw = *(const unsigned int*)(A + (size_t)ci * PLANE + pg);
        Bs[(2 * p) * 130 + ci]     = (unsigned short)(raw & 0xffffu);
        Bs[(2 * p + 1) * 130 + ci] = (unsigned short)(raw >> 16);
    }
}

__device__ __forceinline__ bf16x8 afrag(const unsigned int* __restrict__ BtU,
                                        int r, int ko2) {
    union { unsigned int u[4]; bf16x8 v; } f;
    #pragma unroll
    for (int j = 0; j < 4; ++j) f.u[j] = BtU[r * 65 + ko2 + j];
    return f.v;
}

// ---- fused sep tile: mid-pw over K+1 halo rows (MFMA, relu'd bf16 into
//      Braw LDS), then dw2 via chunked register sliding window; dw output
//      written DIRECTLY to global P (bf16, unscaled -- pw_final applies gs).
template <int K>
__device__ __forceinline__ void
sep_tile(unsigned int* __restrict__ BtU, unsigned short* __restrict__ Braw,
         const unsigned short* __restrict__ Asrc,
         const unsigned short* __restrict__ Wmid,
         const float* __restrict__ wd, int hwt,
         unsigned short* __restrict__ Pout) {
    constexpr int PAD = K / 2, NR = K + 1, NSEG = NR / 2, S = 196;
    int wave = threadIdx.x >> 6, lane = threadIdx.x & 63;
    int q = lane >> 4, mm = lane & 15;
    int r = wave * 16 + mm;
    int rbase = 2 * hwt - PAD;                 // first staged image row
    for (int seg = 0; seg < NSEG; ++seg) {
        if (seg) __syncthreads();              // prev seg's afrag reads done
        stage_bt_z(BtU, Asrc, rbase * 32 + seg * 64);
        __syncthreads();
        f32x4 accB[8];
        #pragma unroll
        for (int i = 0; i < 8; ++i) accB[i] = (f32x4){0.f, 0.f, 0.f, 0.f};
        #pragma unroll
        for (int kb = 0; kb < 4; ++kb) {
            bf16x8 a = afrag(BtU, r, kb * 16 + q * 4);
            #pragma unroll
            for (int nt = 0; nt < 8; ++nt) {
                bf16x8 bv = *(const bf16x8*)(Wmid + (nt * 16 + mm) * CC + kb * 32 + q * 8);
                accB[nt] = __builtin_amdgcn_mfma_f32_16x16x32_bf16(a, bv, accB[nt], 0, 0, 0);
            }
        }
        int pxb = seg * 64 + wave * 16 + q * 4;   // local px within NR rows
        #pragma unroll
        for (int nt = 0; nt < 8; ++nt) {
            int co = nt * 16 + mm;
            ushort4 v;
            v.x = f2us(fmaxf(accB[nt][0], 0.f));   // relu folded (bit-equal to
            v.y = f2us(fmaxf(accB[nt][1], 0.f));   // round-then-relu for bf16)
            v.z = f2us(fmaxf(accB[nt][2], 0.f));
            v.w = f2us(fmaxf(accB[nt][3], 0.f));
            *(ushort4*)(Braw + (size_t)co * S + pxb) = v;
        }
    }
    __syncthreads();                           // Braw complete

    // dw2 KxK: thread (ci, h) computes output row 2*hwt+h, cols 0..31.
    // Chunked 8-col sliding window (R12's spill-safe shape).
    int ci = threadIdx.x & 127, h = threadIdx.x >> 7;
    float wk[K * K];
    #pragma unroll
    for (int i = 0; i < K * K; ++i) wk[i] = wd[ci * K * K + i];
    const unsigned short* rowp = Braw + (size_t)ci * S + h * 32;
    unsigned short* po = Pout + (size_t)ci * PLANE + (2 * hwt + h) * 32;
    #pragma unroll
    for (int w0 = 0; w0 < 32; w0 += 8) {
        float acc[8];
        #pragma unroll
        for (int w = 0; w < 8; ++w) acc[w] = 0.f;
        #pragma unroll
        for (int ky = 0; ky < K; ++ky) {       // input row = h + ky
            float win[16];                     // cols w0-4 .. w0+11
            #pragma unroll
            for (int k = 0; k < 4; ++k) {
                int col = w0 - 4 + 4 * k;      // 4-col groups: all-in or all-out
                if ((unsigned)col < 32u) {
                    ushort4 v = *(const ushort4*)(rowp + ky * 32 + col);
                    win[4*k]   = us2f(v.x);
                    win[4*k+1] = us2f(v.y);
                    win[4*k+2] = us2f(v.z);
                    win[4*k+3] = us2f(v.w);
                } else {
                    win[4*k] = win[4*k+1] = win[4*k+2] = win[4*k+3] = 0.f;
                }
            }
            #pragma unroll
            for (int kx = 0; kx < K; ++kx) {
                float f = wk[ky * K + kx];
                #pragma unroll
                for (int w = 0; w < 8; ++w)
                    acc[w] = fmaf(f, win[w + kx - PAD + 4], acc[w]);
            }
        }
        ushort4 o0, o1;
        o0.x = f2us(acc[0]); o0.y = f2us(acc[1]);
        o0.z = f2us(acc[2]); o0.w = f2us(acc[3]);
        o1.x = f2us(acc[4]); o1.y = f2us(acc[5]);
        o1.z = f2us(acc[6]); o1.w = f2us(acc[7]);
        *(ushort4*)(po + w0)     = o0;
        *(ushort4*)(po + w0 + 4) = o1;
    }
}

// ------------- K2: fused mid-pw + dw2 for sep ops, one op per block.
// grid = BB*32: blk -> (b, opi, hwt); ~512 active blocks = one full-device
// round at 2 blocks/CU (LDS 67KB). No cross-op accumulator, no atomics.
__global__ __launch_bounds__(256) void
k_sep(const unsigned short* __restrict__ A4,
      const unsigned short* __restrict__ A5,
      const unsigned short* __restrict__ Wbf,
      const float* __restrict__ gates,
      const float* __restrict__ wd3, const float* __restrict__ wd5,
      unsigned short* __restrict__ P4, unsigned short* __restrict__ P5) {
    int blk = blockIdx.x;              // b*32 + opi*16 + hwt
    int hwt = blk & 15;
    int opi = (blk >> 4) & 1;
    int b = blk >> 5;
    if (gates[b * 8 + 4 + opi] == 0.f) return;
    __shared__ unsigned int BtU[64 * 65];           // 16.6 KB
    __shared__ unsigned short Braw[128 * 196];      // 50.2 KB
    if (opi == 0)
        sep_tile<3>(BtU, Braw, A4 + (size_t)b * SAMP, Wbf, wd3, hwt,
                    P4 + (size_t)b * SAMP);
    else
        sep_tile<5>(BtU, Braw, A5 + (size_t)b * SAMP, Wbf + 16384, wd5, hwt,
                    P5 + (size_t)b * SAMP);
}

// ------------- K3: final pw, gated instances (gs in Bt); RMW into out when
// pools/skip initialized it, plain store for conv-only samples (front
// skipped the zero-init for those).
__global__ __launch_bounds__(256) void
k_pw_final(const unsigned short* __restrict__ P4,
           const unsigned short* __restrict__ P5,
           const unsigned short* __restrict__ P6,
           const unsigned short* __restrict__ P7,
           const unsigned short* __restrict__ Wbf,
           const float* __restrict__ gates,
           const int* __restrict__ cnum, const int* __restrict__ cops,
           float* __restrict__ out) {
    int blk = blockIdx.x;              // b*16 + hwt
    int hwt = blk & 15;
    int b = blk >> 4;
    int n = cnum[b];
    if (n == 0) return;                // out already holds pools/skip/zeros
    bool poolskip = (gates[b * 8 + 1] != 0.f) | (gates[b * 8 + 2] != 0.f) |
                    (gates[b * 8 + 3] != 0.f);
    int hw0 = hwt * 64;
    int wave = threadIdx.x >> 6, lane = threadIdx.x & 63;
    int q = lane >> 4, mm = lane & 15;
    int r = wave * 16 + mm;
    __shared__ unsigned int BtU[64 * 65];
    f32x4 acc[8];
    #pragma unroll
    for (int i = 0; i < 8; ++i) acc[i] = (f32x4){0.f, 0.f, 0.f, 0.f};
    for (int t = 0; t < n; ++t) {
        int op = cops[b * 4 + t];
        float gs = gates[b * 8 + op] * BN_SCALE;
        const unsigned short* src;
        switch (op) {
            case 4:  src = P4; break;
            case 5:  src = P5; break;
            case 6:  src = P6; break;
            default: src = P7; break;
        }
        if (t) __syncthreads();
        stage_bt(BtU, src + (size_t)b * SAMP, hw0, gs);
        __syncthreads();
        const unsigned short* Wb = Wbf + (op - 2) * 16384;
        #pragma unroll
        for (int kb = 0; kb < 4; ++kb) {
            bf16x8 a = afrag(BtU, r, kb * 16 + q * 4);
            #pragma unroll
            for (int nt = 0; nt < 8; ++nt) {
                bf16x8 bv = *(const bf16x8*)(Wb + (nt * 16 + mm) * CC + kb * 32 + q * 8);
                acc[nt] = __builtin_amdgcn_mfma_f32_16x16x32_bf16(a, bv, acc[nt], 0, 0, 0);
            }
        }
    }
    int hwbase = hw0 + wave * 16 + q * 4;
    if (poolskip) {
        #pragma unroll
        for (int nt = 0; nt < 8; ++nt) {
            int co = nt * 16 + mm;
            float* p = out + (size_t)(b * CC + co) * PLANE + hwbase;
            float4 o = *(float4*)p;
            o.x += acc[nt][0]; o.y += acc[nt][1];
            o.z += acc[nt][2]; o.w += acc[nt][3];
            *(float4*)p = o;
        }
    } else {
        #pragma unroll
        for (int nt = 0; nt < 8; ++nt) {
            int co = nt * 16 + mm;
            float* p = out + (size_t)(b * CC + co) * PLANE + hwbase;
            *(float4*)p = make_float4(acc[nt][0], acc[nt][1],
                                      acc[nt][2], acc[nt][3]);
        }
    }
}

// ---------------------------------------------------------------- launch
extern "C" void kernel_launch(void* const* d_in, const int* in_sizes, int n_in,
                              void* d_out, int out_size, void* d_ws, size_t ws_size,
                              hipStream_t stream) {
    const float* x      = (const float*)d_in[0];
    const float* wlog   = (const float*)d_in[1];
    const float* sc3_d1 = (const float*)d_in[2];
    const float* sc3_p1 = (const float*)d_in[3];
    const float* sc3_d2 = (const float*)d_in[4];
    const float* sc3_p2 = (const float*)d_in[5];
    const float* sc5_d1 = (const float*)d_in[6];
    const float* sc5_p1 = (const float*)d_in[7];
    const float* sc5_d2 = (const float*)d_in[8];
    const float* sc5_p2 = (const float*)d_in[9];
    const float* dc3_d  = (const float*)d_in[10];
    const float* dc3_p  = (const float*)d_in[11];
    const float* dc5_d  = (const float*)d_in[12];
    const float* dc5_p  = (const float*)d_in[13];
    const void* topp    = d_in[14];

    float* out  = (float*)d_out;
    float* outw = out + NOUT0;

    float* gates = (float*)d_ws;
    int*   cnum  = (int*)((char*)d_ws + 2048);
    int*   cops  = (int*)((char*)d_ws + 2304);
    unsigned short* Wbf  = (unsigned short*)((char*)d_ws + 4096);   // 6*32KB
    unsigned short* base = (unsigned short*)((char*)d_ws + 200704);
    unsigned short* A4 = base;
    unsigned short* A5 = base + (size_t)NOUT0;
    unsigned short* P4 = base + (size_t)NOUT0 * 2;
    unsigned short* P5 = base + (size_t)NOUT0 * 3;
    unsigned short* P6 = base + (size_t)NOUT0 * 4;
    unsigned short* P7 = base + (size_t)NOUT0 * 5;

    k_front_all<<<FRONT_MAIN + 385, 256, 0, stream>>>(
        x, sc3_d1, sc5_d1, dc3_d, dc5_d,
        wlog, topp,
        sc3_p1, sc5_p1, sc3_p2, sc5_p2, dc3_p, dc5_p,
        gates, cnum, cops, outw, Wbf,
        out, A4, A5, P6, P7);
    k_sep<<<BB * 32, 256, 0, stream>>>(A4, A5, Wbf, gates,
                                       sc3_d2, sc5_d2, P4, P5);
    k_pw_final<<<BB * 16, 256, 0, stream>>>(P4, P5, P6, P7, Wbf,
                                            gates, cnum, cops, out);
}